// Round 2
// baseline (407.193 us; speedup 1.0000x reference)
//
#include <hip/hip_runtime.h>

#define TD_ 512
#define B_  32
#define H_  512
#define TE_ 2048

typedef __attribute__((ext_vector_type(8))) short bf16x8;
typedef __attribute__((ext_vector_type(4))) short bf16x4;
typedef __attribute__((ext_vector_type(4))) float f32x4;

__device__ __forceinline__ short f2b(float f){
  union { float f; unsigned u; } v; v.f = f;
  return (short)((v.u + 0x7fffu + ((v.u >> 16) & 1u)) >> 16);  // RNE f32->bf16
}

// encoder_out (B,H,TE) f32 -> Ebf (B,H,TE) bf16 (straight cast)
//                          -> Ebt (B,TE,H) bf16 (transposed)
__global__ __launch_bounds__(256) void k_prep(const float* __restrict__ E,
                                              short* __restrict__ Ebf,
                                              short* __restrict__ Ebt){
  __shared__ short tile[64][72];
  int b = blockIdx.z;
  int h0 = blockIdx.y << 6, e0 = blockIdx.x << 6;
  int y = threadIdx.x >> 2;      // 0..63
  int x = threadIdx.x & 3;       // 0..3 (16 elems each)
  const float* Ein = E + ((long)b*H_ + h0 + y)*TE_ + e0 + x*16;
  short* Eo = Ebf + ((long)b*H_ + h0 + y)*TE_ + e0 + x*16;
  #pragma unroll
  for (int q=0;q<2;q++){
    f32x4 v0 = *(const f32x4*)(Ein + q*8);
    f32x4 v1 = *(const f32x4*)(Ein + q*8 + 4);
    bf16x8 o;
    o[0]=f2b(v0[0]); o[1]=f2b(v0[1]); o[2]=f2b(v0[2]); o[3]=f2b(v0[3]);
    o[4]=f2b(v1[0]); o[5]=f2b(v1[1]); o[6]=f2b(v1[2]); o[7]=f2b(v1[3]);
    *(bf16x8*)(Eo + q*8) = o;
    *(bf16x8*)(&tile[y][x*16 + q*8]) = o;
  }
  __syncthreads();
  // transposed out: row e = e0+y, cols h = h0 + x*16 .. +16
  short* Ob = Ebt + ((long)b*TE_ + e0 + y)*H_ + h0 + x*16;
  bf16x8 u0, u1;
  #pragma unroll
  for (int i2=0;i2<8;i2++) u0[i2] = tile[x*16 + i2][y];
  #pragma unroll
  for (int i2=0;i2<8;i2++) u1[i2] = tile[x*16 + 8 + i2][y];
  *(bf16x8*)(Ob) = u0;
  *(bf16x8*)(Ob + 8) = u1;
}

// Fused: per (b, 64-row t-block): GEMM1 + exp/NS/div epilogue + GEMM2 (ctx^T) + deferred normalize.
__global__ __launch_bounds__(512,1) void k_fused(
    const float* __restrict__ oh, const short* __restrict__ Ebt,
    const short* __restrict__ Ebf, const float* __restrict__ S,
    float* __restrict__ NS, float* __restrict__ ctx){
  __shared__ short As[64*512];   // [t][h] bf16, XOR-swizzled rows
  __shared__ short Ps[64*128];   // [t][e-chunk] bf16, XOR-swizzled rows
  __shared__ float rsLds[64];

  // XCD-local decode: all 8 t-blocks of batch b land on one XCD
  int wg = blockIdx.x;
  int xcd = wg & 7, i = wg >> 3;
  int b = xcd*4 + (i & 3);
  int t0 = (i >> 2) << 6;

  int tid = threadIdx.x, lane = tid & 63, w = tid >> 6;
  int g = lane >> 4, lr = lane & 15;
  int wr = w >> 2, wc = w & 3;   // GEMM1 wave split: 32t x 32e

  if (tid < 64) rsLds[tid] = 0.f;

  // stage A: oh (TD,B,H) f32 -> As [64][512] bf16 swizzled
  {
    const float* ohb = oh + (long)t0*(B_*H_) + (long)b*H_;
    #pragma unroll
    for (int it=0; it<8; ++it){
      int c = it*512 + tid;          // 4096 16B-chunks
      int row = c >> 6, cc = c & 63;
      const float* src = ohb + (long)row*(B_*H_) + cc*8;
      f32x4 v0 = *(const f32x4*)src;
      f32x4 v1 = *(const f32x4*)(src+4);
      bf16x8 o;
      o[0]=f2b(v0[0]); o[1]=f2b(v0[1]); o[2]=f2b(v0[2]); o[3]=f2b(v0[3]);
      o[4]=f2b(v1[0]); o[5]=f2b(v1[1]); o[6]=f2b(v1[2]); o[7]=f2b(v1[3]);
      *(bf16x8*)(As + row*512 + ((cc ^ (row & 7)) << 3)) = o;
    }
  }
  __syncthreads();

  const short* EbtB = Ebt + (long)b*TE_*H_;
  const short* EbfB = Ebf + (long)b*H_*TE_;
  const float* Sb = S + (long)b*TD_*TE_;
  float* NSb = NS + (long)b*TD_*TE_;

  const f32x4 fz = {0.f,0.f,0.f,0.f};
  f32x4 accC[4][4];
  #pragma unroll
  for (int m=0;m<4;m++)
    #pragma unroll
    for (int n=0;n<4;n++) accC[m][n] = fz;
  float rsum[2][4];
  #pragma unroll
  for (int m=0;m<2;m++)
    #pragma unroll
    for (int r=0;r<4;r++) rsum[m][r] = 0.f;

  for (int ec=0; ec<16; ++ec){
    int e0 = ec << 7;
    // ---- GEMM1: scores 64x128 tile, wave owns 32x32 (2x2 frags) ----
    f32x4 acc1[2][2];
    acc1[0][0]=fz; acc1[0][1]=fz; acc1[1][0]=fz; acc1[1][1]=fz;
    #pragma unroll
    for (int ks=0; ks<16; ++ks){
      bf16x8 af[2], bfv[2];
      #pragma unroll
      for (int m=0;m<2;m++){
        int t1 = wr*32 + m*16 + lr;
        int byte_ = t1*1024 + ((ks*64 + (g<<4)) ^ ((lr & 7) << 4));
        af[m] = *(const bf16x8*)((const char*)As + byte_);
      }
      #pragma unroll
      for (int n=0;n<2;n++){
        int e1 = e0 + wc*32 + n*16 + lr;
        bfv[n] = *(const bf16x8*)(EbtB + (long)e1*H_ + ks*32 + (g<<3));
      }
      acc1[0][0] = __builtin_amdgcn_mfma_f32_16x16x32_bf16(af[0], bfv[0], acc1[0][0], 0,0,0);
      acc1[0][1] = __builtin_amdgcn_mfma_f32_16x16x32_bf16(af[0], bfv[1], acc1[0][1], 0,0,0);
      acc1[1][0] = __builtin_amdgcn_mfma_f32_16x16x32_bf16(af[1], bfv[0], acc1[1][0], 0,0,0);
      acc1[1][1] = __builtin_amdgcn_mfma_f32_16x16x32_bf16(af[1], bfv[1], acc1[1][1], 0,0,0);
    }
    // ---- epilogue: exp, NS out, av = ta/S, P->LDS (swizzled), rowsum ----
    #pragma unroll
    for (int m=0;m<2;m++){
      #pragma unroll
      for (int r=0;r<4;r++){
        int tl = wr*32 + m*16 + g*4 + r;
        long rowoff = (long)(t0 + tl)*TE_ + e0;
        float rp = 0.f;
        #pragma unroll
        for (int n=0;n<2;n++){
          int el = wc*32 + n*16 + lr;
          long off = rowoff + el;
          float sv = Sb[off];
          float ta = __expf(acc1[m][n][r]);
          NSb[off] = ta + sv;
          float av = ta * __builtin_amdgcn_rcpf(sv);
          *(short*)((char*)Ps + tl*256 + ((el*2) ^ ((tl & 7) << 4))) = f2b(av);
          rp += av;
        }
        rsum[m][r] += rp;
      }
    }
    __syncthreads();
    // ---- GEMM2: ctx^T[h,t] += E[h,e-chunk] (A, global bf16) x P[t,e-chunk] (B, LDS) ----
    #pragma unroll
    for (int ks2=0; ks2<4; ++ks2){
      bf16x8 pb[4];
      #pragma unroll
      for (int n=0;n<4;n++){
        int tl = n*16 + lr;
        pb[n] = *(const bf16x8*)((const char*)Ps + tl*256 + ((ks2*64 + (g<<4)) ^ ((tl & 7) << 4)));
      }
      #pragma unroll
      for (int m=0;m<4;m++){
        int h = w*64 + m*16 + lr;
        bf16x8 ea = *(const bf16x8*)(EbfB + (long)h*TE_ + e0 + ks2*32 + (g<<3));
        #pragma unroll
        for (int n=0;n<4;n++)
          accC[m][n] = __builtin_amdgcn_mfma_f32_16x16x32_bf16(ea, pb[n], accC[m][n], 0,0,0);
      }
    }
    __syncthreads();   // Ps consumed before next chunk's epilogue rewrites it
  }

  // ---- rowsum: shfl-reduce over lr, cross-wave via LDS atomics ----
  #pragma unroll
  for (int m=0;m<2;m++){
    #pragma unroll
    for (int r=0;r<4;r++){
      float rp = rsum[m][r];
      rp += __shfl_xor(rp,1); rp += __shfl_xor(rp,2);
      rp += __shfl_xor(rp,4); rp += __shfl_xor(rp,8);
      if (lr == 0) atomicAdd(&rsLds[wr*32 + m*16 + g*4 + r], rp);
    }
  }
  __syncthreads();

  // ---- normalize + write ctx (TD,B,H) ----
  #pragma unroll
  for (int n=0;n<4;n++){
    float inv = __builtin_amdgcn_rcpf(rsLds[n*16 + lr]);
    int t = t0 + n*16 + lr;
    #pragma unroll
    for (int m=0;m<4;m++){
      f32x4 v = accC[m][n];
      v[0]*=inv; v[1]*=inv; v[2]*=inv; v[3]*=inv;
      *(f32x4*)(ctx + (long)t*(B_*H_) + (long)b*H_ + w*64 + m*16 + g*4) = v;
    }
  }
}

extern "C" void kernel_launch(void* const* d_in, const int* in_sizes, int n_in,
                              void* d_out, int out_size, void* d_ws, size_t ws_size,
                              hipStream_t stream){
  const float* oh = (const float*)d_in[0];   // (TD,B,H)
  const float* E  = (const float*)d_in[1];   // (B,H,TE)
  const float* S  = (const float*)d_in[2];   // (B,TD,TE)
  float* out_ctx = (float*)d_out;                       // (TD,B,H)
  float* out_ns  = out_ctx + (long)TD_*B_*H_;           // (B,TD,TE)

  char* ws = (char*)d_ws;
  short* Ebt = (short*)ws;                               // (B,TE,H) bf16: 64 MiB
  short* Ebf = (short*)(ws + (size_t)B_*TE_*H_*2);       // (B,H,TE) bf16: 64 MiB

  k_prep<<<dim3(TE_/64, H_/64, B_), 256, 0, stream>>>(E, Ebf, Ebt);
  k_fused<<<dim3(256), 512, 0, stream>>>(oh, Ebt, Ebf, S, out_ns, out_ctx);
}

// Round 3
// 271.068 us; speedup vs baseline: 1.5022x; 1.5022x over previous
//
#include <hip/hip_runtime.h>

#define TD_ 512
#define B_  32
#define H_  512
#define TE_ 2048

typedef __attribute__((ext_vector_type(8))) short bf16x8;
typedef __attribute__((ext_vector_type(4))) short bf16x4;
typedef __attribute__((ext_vector_type(4))) float f32x4;

__device__ __forceinline__ short f2b(float f){
  union { float f; unsigned u; } v; v.f = f;
  return (short)((v.u + 0x7fffu + ((v.u >> 16) & 1u)) >> 16);  // RNE f32->bf16
}

__device__ __forceinline__ void gload16(const void* g, void* l){
  __builtin_amdgcn_global_load_lds((const __attribute__((address_space(1))) void*)g,
                                   (__attribute__((address_space(3))) void*)l,
                                   16, 0, 0);
}

// outputs_hidden (TD,B,H) f32 -> Abf (B,TD,H) bf16
__global__ __launch_bounds__(256) void k_cvtA(const float* __restrict__ oh,
                                              short* __restrict__ Abf){
  long base = ((long)blockIdx.x * 256 + threadIdx.x) * 4;
  int t = (int)(base >> 14);
  int rem = (int)(base & 16383);
  int b = rem >> 9, h = rem & 511;
  f32x4 v = *(const f32x4*)(oh + base);
  bf16x4 o;
  o[0]=f2b(v[0]); o[1]=f2b(v[1]); o[2]=f2b(v[2]); o[3]=f2b(v[3]);
  *(bf16x4*)(Abf + (long)b*TD_*H_ + (long)t*H_ + h) = o;
}

// encoder_out (B,H,TE) f32 -> Ebf (B,H,TE) bf16 (cast) + Ebt (B,TE,H) bf16 (transposed)
__global__ __launch_bounds__(256) void k_prep(const float* __restrict__ E,
                                              short* __restrict__ Ebf,
                                              short* __restrict__ Ebt){
  __shared__ short tile[64][72];
  int b = blockIdx.z;
  int h0 = blockIdx.y << 6, e0 = blockIdx.x << 6;
  int y = threadIdx.x >> 2;      // 0..63
  int x = threadIdx.x & 3;       // 0..3
  const float* Ein = E + ((long)b*H_ + h0 + y)*TE_ + e0 + x*16;
  short* Eo = Ebf + ((long)b*H_ + h0 + y)*TE_ + e0 + x*16;
  #pragma unroll
  for (int q=0;q<2;q++){
    f32x4 v0 = *(const f32x4*)(Ein + q*8);
    f32x4 v1 = *(const f32x4*)(Ein + q*8 + 4);
    bf16x8 o;
    o[0]=f2b(v0[0]); o[1]=f2b(v0[1]); o[2]=f2b(v0[2]); o[3]=f2b(v0[3]);
    o[4]=f2b(v1[0]); o[5]=f2b(v1[1]); o[6]=f2b(v1[2]); o[7]=f2b(v1[3]);
    *(bf16x8*)(Eo + q*8) = o;
    *(bf16x8*)(&tile[y][x*16 + q*8]) = o;
  }
  __syncthreads();
  short* Ob = Ebt + ((long)b*TE_ + e0 + y)*H_ + h0 + x*16;
  bf16x8 u0, u1;
  #pragma unroll
  for (int i2=0;i2<8;i2++) u0[i2] = tile[x*16 + i2][y];
  #pragma unroll
  for (int i2=0;i2<8;i2++) u1[i2] = tile[x*16 + 8 + i2][y];
  *(bf16x8*)(Ob) = u0;
  *(bf16x8*)(Ob + 8) = u1;
}

// GEMM1 + fused epilogue. A=Abf (B,TD,H), B=Ebt (B,TE,H), both gload_lds with
// inverse-swizzled source; LDS tiles [128][64] bf16, byte XOR (row&7)<<4.
__global__ __launch_bounds__(256) void k_scores(
    const short* __restrict__ Abf, const short* __restrict__ Ebt,
    const float* __restrict__ S, float* __restrict__ NS,
    short* __restrict__ att, float* __restrict__ rs){
  __shared__ short As[128*64];
  __shared__ short Bs[128*64];
  int b = blockIdx.z;
  int t0 = blockIdx.y << 7;
  int e0 = blockIdx.x << 7;
  int tid = threadIdx.x, lane = tid & 63, w = tid >> 6;
  int wr = w >> 1, wc = w & 1, g = lane >> 4, lr = lane & 15;

  const short* Ag = Abf + (long)b*TD_*H_ + (long)t0*H_;
  const short* Bg = Ebt + (long)b*TE_*H_ + (long)e0*H_;

  const f32x4 fz = {0.f,0.f,0.f,0.f};
  f32x4 acc[4][4];
  #pragma unroll
  for (int m=0;m<4;m++)
    #pragma unroll
    for (int n=0;n<4;n++) acc[m][n] = fz;

  for (int k0=0;k0<H_;k0+=64){
    __syncthreads();
    #pragma unroll
    for (int p=0;p<4;p++){
      int cb = (w*4 + p)*64;        // wave-uniform base, 16B units
      int c = cb + lane;
      int row = c >> 3;
      int cc = (c & 7) ^ (row & 7); // inverse-swizzled source column
      gload16(Ag + (long)row*H_ + k0 + cc*8, (char*)As + cb*16);
      gload16(Bg + (long)row*H_ + k0 + cc*8, (char*)Bs + cb*16);
    }
    __syncthreads();
    #pragma unroll
    for (int ks=0;ks<2;ks++){
      bf16x8 af[4], bfr[4];
      #pragma unroll
      for (int m=0;m<4;m++){
        int r_ = wr*64 + m*16 + lr;
        af[m] = *(const bf16x8*)((const char*)As + r_*128 + ((ks*64 + g*16) ^ ((r_ & 7) << 4)));
      }
      #pragma unroll
      for (int n=0;n<4;n++){
        int r_ = wc*64 + n*16 + lr;
        bfr[n] = *(const bf16x8*)((const char*)Bs + r_*128 + ((ks*64 + g*16) ^ ((r_ & 7) << 4)));
      }
      #pragma unroll
      for (int m=0;m<4;m++)
        #pragma unroll
        for (int n=0;n<4;n++)
          acc[m][n] = __builtin_amdgcn_mfma_f32_16x16x32_bf16(af[m], bfr[n], acc[m][n], 0, 0, 0);
    }
  }

  const float* Sb = S + (long)b*TD_*TE_;
  float* NSb = NS + (long)b*TD_*TE_;
  short* attb = att + (long)b*TD_*TE_;
  #pragma unroll
  for (int m=0;m<4;m++){
    #pragma unroll
    for (int r=0;r<4;r++){
      int t = t0 + wr*64 + m*16 + g*4 + r;
      float rp = 0.f;
      #pragma unroll
      for (int n=0;n<4;n++){
        int e = e0 + wc*64 + n*16 + lr;
        long off = (long)t*TE_ + e;
        float sv = Sb[off];
        float ta = __expf(acc[m][n][r]);
        NSb[off] = ta + sv;
        float av = ta * __builtin_amdgcn_rcpf(sv);
        attb[off] = f2b(av);
        rp += av;
      }
      rp += __shfl_xor(rp, 1);
      rp += __shfl_xor(rp, 2);
      rp += __shfl_xor(rp, 4);
      rp += __shfl_xor(rp, 8);
      if (lr == 0) atomicAdd(&rs[b*TD_ + t], rp);
    }
  }
}

// GEMM2: ctx[t,h] = (att[t,:].E[h,:]) / rs[t], K=TE. A=att bf16, B=Ebf bf16,
// both gload_lds with swizzle. Output (TD,B,H).
__global__ __launch_bounds__(256) void k_ctx(
    const short* __restrict__ att, const short* __restrict__ Ebf,
    const float* __restrict__ rs, float* __restrict__ ctx){
  __shared__ short As[128*64];
  __shared__ short Bs[128*64];
  int b = blockIdx.z;
  int t0 = blockIdx.y << 7;
  int h0 = blockIdx.x << 7;
  int tid = threadIdx.x, lane = tid & 63, w = tid >> 6;
  int wr = w >> 1, wc = w & 1, g = lane >> 4, lr = lane & 15;

  const short* Ag = att + (long)b*TD_*TE_ + (long)t0*TE_;
  const short* Bg = Ebf + (long)b*H_*TE_ + (long)h0*TE_;

  const f32x4 fz = {0.f,0.f,0.f,0.f};
  f32x4 acc[4][4];
  #pragma unroll
  for (int m=0;m<4;m++)
    #pragma unroll
    for (int n=0;n<4;n++) acc[m][n] = fz;

  for (int k0=0;k0<TE_;k0+=64){
    __syncthreads();
    #pragma unroll
    for (int p=0;p<4;p++){
      int cb = (w*4 + p)*64;
      int c = cb + lane;
      int row = c >> 3;
      int cc = (c & 7) ^ (row & 7);
      gload16(Ag + (long)row*TE_ + k0 + cc*8, (char*)As + cb*16);
      gload16(Bg + (long)row*TE_ + k0 + cc*8, (char*)Bs + cb*16);
    }
    __syncthreads();
    #pragma unroll
    for (int ks=0;ks<2;ks++){
      bf16x8 af[4], bfr[4];
      #pragma unroll
      for (int m=0;m<4;m++){
        int r_ = wr*64 + m*16 + lr;
        af[m] = *(const bf16x8*)((const char*)As + r_*128 + ((ks*64 + g*16) ^ ((r_ & 7) << 4)));
      }
      #pragma unroll
      for (int n=0;n<4;n++){
        int r_ = wc*64 + n*16 + lr;
        bfr[n] = *(const bf16x8*)((const char*)Bs + r_*128 + ((ks*64 + g*16) ^ ((r_ & 7) << 4)));
      }
      #pragma unroll
      for (int m=0;m<4;m++)
        #pragma unroll
        for (int n=0;n<4;n++)
          acc[m][n] = __builtin_amdgcn_mfma_f32_16x16x32_bf16(af[m], bfr[n], acc[m][n], 0, 0, 0);
    }
  }

  #pragma unroll
  for (int m=0;m<4;m++){
    #pragma unroll
    for (int r=0;r<4;r++){
      int t = t0 + wr*64 + m*16 + g*4 + r;
      float inv = __builtin_amdgcn_rcpf(rs[b*TD_ + t]);
      #pragma unroll
      for (int n=0;n<4;n++){
        int h = h0 + wc*64 + n*16 + lr;
        ctx[(long)t*B_*H_ + (long)b*H_ + h] = acc[m][n][r] * inv;
      }
    }
  }
}

extern "C" void kernel_launch(void* const* d_in, const int* in_sizes, int n_in,
                              void* d_out, int out_size, void* d_ws, size_t ws_size,
                              hipStream_t stream){
  const float* oh = (const float*)d_in[0];   // (TD,B,H)
  const float* E  = (const float*)d_in[1];   // (B,H,TE)
  const float* S  = (const float*)d_in[2];   // (B,TD,TE)
  float* out_ctx = (float*)d_out;                       // (TD,B,H)
  float* out_ns  = out_ctx + (long)TD_*B_*H_;           // (B,TD,TE)

  char* ws = (char*)d_ws;
  size_t offEbt = 0;
  size_t offEbf = offEbt + (size_t)B_*TE_*H_*2;   // 64 MiB
  size_t offA   = offEbf + (size_t)B_*H_*TE_*2;   // 64 MiB
  size_t offAt  = offA   + (size_t)B_*TD_*H_*2;   // 16 MiB
  size_t offRs  = offAt  + (size_t)B_*TD_*TE_*2;  // 64 MiB
  short* Ebt  = (short*)(ws + offEbt);
  short* Ebf  = (short*)(ws + offEbf);
  short* Abf  = (short*)(ws + offA);
  short* attw = (short*)(ws + offAt);
  float* rsums= (float*)(ws + offRs);

  hipMemsetAsync(rsums, 0, (size_t)B_*TD_*4, stream);
  k_cvtA<<<dim3((TD_*B_*H_)/(256*4)), 256, 0, stream>>>(oh, Abf);
  k_prep<<<dim3(TE_/64, H_/64, B_), 256, 0, stream>>>(E, Ebf, Ebt);
  k_scores<<<dim3(TE_/128, TD_/128, B_), 256, 0, stream>>>(Abf, Ebt, S, out_ns, attw, rsums);
  k_ctx<<<dim3(H_/128, TD_/128, B_), 256, 0, stream>>>(attw, Ebf, rsums, out_ctx);
}